// Round 9
// baseline (85.964 us; speedup 1.0000x reference)
//
#include <hip/hip_runtime.h>
#include <hip/hip_fp16.h>

#define C_    256
#define H_    200
#define W_    200
#define HW    (H_*W_)        // 40000
#define CHW   ((size_t)C_*HW)
#define PWB   7
#define BINS  49
#define NSMP  196            // 49 bins * 4 subsamples, bin-major

// ============ kernel 1: NCHW fp32 -> NHWC fp16 transpose ============
// input is read exactly once -> non-temporal (keep L3 free for ws)
__global__ __launch_bounds__(256) void nchw_to_nhwc_h(
    const float* __restrict__ in, __half* __restrict__ wsp)
{
    __shared__ float t[64][65];
    const int pgrp = blockIdx.x % 625;          // 625 * 64 = 40000 pixels
    const int cgrp = (blockIdx.x / 625) & 3;    // 4 * 64 = 256 channels
    const int n    = blockIdx.x / 2500;
    const int p0 = pgrp * 64, c0 = cgrp * 64;
    const int tx = threadIdx.x & 63;
    const int ty = threadIdx.x >> 6;            // 0..3

    const float* src = in + (size_t)n * CHW + (size_t)c0 * HW + p0;
    #pragma unroll
    for (int i = 0; i < 16; ++i) {
        const int c = ty + 4 * i;
        t[tx][c] = __builtin_nontemporal_load(&src[(size_t)c * HW + tx]);
    }
    __syncthreads();
    __half* dst = wsp + (size_t)n * CHW + (size_t)p0 * C_ + c0;
    #pragma unroll
    for (int i = 0; i < 16; ++i) {
        const int p = ty + 4 * i;
        dst[(size_t)p * C_ + tx] = __float2half(t[p][tx]);  // normal: stay cached
    }
}

// ============ kernel 2: gather in fp16 NHWC, wave-uniform samples ============
typedef struct { int o; float w; } OW;          // 8B -> broadcast ds_read_b64

__global__ __launch_bounds__(256) void roialign_nhwc_h2(
    const __half* __restrict__ wsp,  // [4][40000][256] fp16
    const float* __restrict__ rois,  // [K][5]
    float* __restrict__ out,         // [K][256][7][7]
    int K)
{
    __shared__ OW     s_ow[NSMP][4];            // 6.27 KB
    __shared__ __half s_out[BINS][130];         // 12.74 KB (pad 130: conflict-free)

    // halves of one roi are K apart; K=1000 = 0 mod 8 -> same XCD -> shared L2
    const int k    = blockIdx.x % K;
    const int half = blockIdx.x / K;

    const float rx1 = rois[k*5 + 1];
    const float ry1 = rois[k*5 + 2];
    const float rx2 = rois[k*5 + 3];
    const float ry2 = rois[k*5 + 4];
    const int  bidx = (int)rois[k*5 + 0];

    // ALIGNED=True, identical op order to validated rounds
    const float sx = __fsub_rn(__fmul_rn(rx1, 0.25f), 0.5f);
    const float sy = __fsub_rn(__fmul_rn(ry1, 0.25f), 0.5f);
    const float bw = __fdiv_rn(__fmul_rn(__fsub_rn(rx2, rx1), 0.25f), 7.0f);
    const float bh = __fdiv_rn(__fmul_rn(__fsub_rn(ry2, ry1), 0.25f), 7.0f);

    const int tid = threadIdx.x;

    // ---- phase 1: 196 samples -> 4 {pixel offset, weight} pairs each ----
    if (tid < NSMP) {
        const int bin = tid >> 2, q = tid & 3;
        const int ph = bin / PWB, pw = bin - ph * PWB;
        const float cy = (float)ph + ((q >> 1) ? 0.75f : 0.25f);
        const float cx = (float)pw + ((q & 1)  ? 0.75f : 0.25f);
        const float fy = __fadd_rn(sy, __fmul_rn(cy, bh));
        const float fx = __fadd_rn(sx, __fmul_rn(cx, bw));

        const bool valid = (fy >= -1.0f) && (fy <= (float)H_) &&
                           (fx >= -1.0f) && (fx <= (float)W_);

        const float y = fminf(fmaxf(fy, 0.0f), (float)(H_ - 1));
        const float x = fminf(fmaxf(fx, 0.0f), (float)(W_ - 1));
        const int y0 = (int)floorf(y);
        const int x0 = (int)floorf(x);
        const int y1 = min(y0 + 1, H_ - 1);
        const int x1 = min(x0 + 1, W_ - 1);
        const float ly = y - (float)y0;
        const float lx = x - (float)x0;
        const float hy = 1.0f - ly, hx = 1.0f - lx;

        float w00 = hy*hx, w01 = hy*lx, w10 = ly*hx, w11 = ly*lx;
        if (!valid) { w00 = w01 = w10 = w11 = 0.0f; }

        s_ow[tid][0].o = y0 * W_ + x0;  s_ow[tid][0].w = w00;
        s_ow[tid][1].o = y0 * W_ + x1;  s_ow[tid][1].w = w01;
        s_ow[tid][2].o = y1 * W_ + x0;  s_ow[tid][2].w = w10;
        s_ow[tid][3].o = y1 * W_ + x1;  s_ow[tid][3].w = w11;
    }
    __syncthreads();

    // ---- phase 2: wave = bin, lane = channel pair (half2) ----
    const int wv   = tid >> 6;                  // 0..3
    const int lane = tid & 63;
    // lane covers channels (half*128 + 2*lane, +1); one wave-instr = 256B burst
    const __half2* __restrict__ img2 =
        (const __half2*)(wsp + (size_t)bidx * CHW) + (half * 64 + lane);

    #pragma unroll 2
    for (int bin = wv; bin < BINS; bin += 4) {
        float a0 = 0.0f, a1 = 0.0f;
        #pragma unroll
        for (int s4 = 0; s4 < 4; ++s4) {
            #pragma unroll
            for (int q = 0; q < 4; ++q) {
                const OW ow = s_ow[bin * 4 + s4][q];
                // wave-uniform -> SGPR: saddr addressing, scalar weight
                const int   o  = __builtin_amdgcn_readfirstlane(ow.o);
                const float wq = __uint_as_float(
                    __builtin_amdgcn_readfirstlane(__float_as_uint(ow.w)));
                const float2 f = __half22float2(img2[(size_t)o * 128]);
                a0 = fmaf(wq, f.x, a0);
                a1 = fmaf(wq, f.y, a1);
            }
        }
        *(__half2*)&s_out[bin][2 * lane] =
            __floats2half2_rn(a0 * 0.25f, a1 * 0.25f);
    }
    __syncthreads();

    // ---- coalesced output write: [ch][bin] order, non-temporal ----
    float* __restrict__ ob = out + ((size_t)k * C_ + half * 128) * BINS;
    #pragma unroll 1
    for (int e = tid; e < 128 * BINS; e += 256) {
        const int ch = e / BINS, bn = e - ch * BINS;
        __builtin_nontemporal_store(__half2float(s_out[bn][ch]), &ob[e]);
    }
}

// ============ fallback (round-4 kernel, fp32 direct) ============
#define CSPLIT 4
#define CB     (C_/CSPLIT)
#define NCG    5
typedef struct __attribute__((aligned(4))) { float x, y; } f2u;

__global__ __launch_bounds__(256) void roialign_fwd_fb(
    const float* __restrict__ input, const float* __restrict__ rois,
    float* __restrict__ out, int K)
{
    const int k  = blockIdx.x / CSPLIT;
    const int cs = blockIdx.x - k * CSPLIT;
    if (k >= K) return;
    const int tid = threadIdx.x;
    const int bin = tid % BINS;
    const int cg  = tid / BINS;
    if (cg >= NCG) return;

    const float rx1 = rois[k*5+1], ry1 = rois[k*5+2];
    const float rx2 = rois[k*5+3], ry2 = rois[k*5+4];
    const int  bidx = (int)rois[k*5+0];
    const float sx = __fsub_rn(__fmul_rn(rx1,0.25f),0.5f);
    const float sy = __fsub_rn(__fmul_rn(ry1,0.25f),0.5f);
    const float bw = __fdiv_rn(__fmul_rn(__fsub_rn(rx2,rx1),0.25f),7.0f);
    const float bh = __fdiv_rn(__fmul_rn(__fsub_rn(ry2,ry1),0.25f),7.0f);
    const int ph = bin / PWB, pw = bin - ph * PWB;

    int off0[4], off1[4];
    float wA0[4], wB0[4], wA1[4], wB1[4];
    #pragma unroll
    for (int q = 0; q < 4; ++q) {
        const float cy = (float)ph + ((q >> 1) ? 0.75f : 0.25f);
        const float cx = (float)pw + ((q & 1)  ? 0.75f : 0.25f);
        const float fy = __fadd_rn(sy, __fmul_rn(cy, bh));
        const float fx = __fadd_rn(sx, __fmul_rn(cx, bw));
        const bool valid = (fy >= -1.0f) && (fy <= (float)H_) &&
                           (fx >= -1.0f) && (fx <= (float)W_);
        const float y = fminf(fmaxf(fy, 0.0f), (float)(H_-1));
        const float x = fminf(fmaxf(fx, 0.0f), (float)(W_-1));
        const int y0 = (int)floorf(y);
        const int x0 = (int)floorf(x);
        const int y1 = min(y0 + 1, H_-1);
        const float ly = y - (float)y0, lx = x - (float)x0;
        const float hy = 1.0f - ly, hx = 1.0f - lx;
        float w00 = hy*hx, w01 = hy*lx, w10 = ly*hx, w11 = ly*lx;
        if (!valid) { w00 = w01 = w10 = w11 = 0.0f; }
        const int xb = min(x0, W_-2);
        const bool xcl = (x0 != xb);
        wA0[q] = xcl ? 0.0f : w00;  wB0[q] = xcl ? w00 : w01;
        wA1[q] = xcl ? 0.0f : w10;  wB1[q] = xcl ? w10 : w11;
        off0[q] = y0 * W_ + xb;     off1[q] = y1 * W_ + xb;
    }
    const float* __restrict__ img  = input + ((size_t)bidx*C_ + cs*CB) * HW;
    float* __restrict__       outk = out   + ((size_t)k   *C_ + cs*CB) * BINS;
    #pragma unroll 2
    for (int c = cg; c < CB; c += NCG) {
        const float* __restrict__ ch = img + (size_t)c * HW;
        float acc = 0.0f;
        #pragma unroll
        for (int q = 0; q < 4; ++q) {
            const f2u p0 = *(const f2u*)(ch + off0[q]);
            const f2u p1 = *(const f2u*)(ch + off1[q]);
            acc += wA0[q]*p0.x + wB0[q]*p0.y + wA1[q]*p1.x + wB1[q]*p1.y;
        }
        outk[c * BINS + bin] = acc * 0.25f;
    }
}

extern "C" void kernel_launch(void* const* d_in, const int* in_sizes, int n_in,
                              void* d_out, int out_size, void* d_ws, size_t ws_size,
                              hipStream_t stream) {
    const float* input = (const float*)d_in[0];
    const float* rois  = (const float*)d_in[1];
    float* out = (float*)d_out;
    const int K = in_sizes[1] / 5;
    const int N = in_sizes[0] / (int)CHW;       // 4 images

    const size_t need = (size_t)N * CHW * sizeof(__half);   // 81.92 MB
    if (ws_size >= need) {
        __half* wsp = (__half*)d_ws;
        nchw_to_nhwc_h<<<N * 2500, 256, 0, stream>>>(input, wsp);
        roialign_nhwc_h2<<<K * 2, 256, 0, stream>>>(wsp, rois, out, K);
    } else {
        roialign_fwd_fb<<<K * CSPLIT, 256, 0, stream>>>(input, rois, out, K);
    }
}

// Round 10
// 83.089 us; speedup vs baseline: 1.0346x; 1.0346x over previous
//
#include <hip/hip_runtime.h>
#include <hip/hip_fp16.h>

#define C_    256
#define H_    200
#define W_    200
#define HW    (H_*W_)        // 40000
#define CHW   ((size_t)C_*HW)
#define PWB   7
#define BINS  49
#define NSMP  196            // 49 bins * 4 subsamples, bin-major

// ============ kernel 1: NCHW fp32 -> NHWC fp16 transpose ============
__global__ __launch_bounds__(256) void nchw_to_nhwc_h(
    const float* __restrict__ in, __half* __restrict__ wsp)
{
    __shared__ float t[64][65];
    const int pgrp = blockIdx.x % 625;          // 625 * 64 = 40000 pixels
    const int cgrp = (blockIdx.x / 625) & 3;    // 4 * 64 = 256 channels
    const int n    = blockIdx.x / 2500;
    const int p0 = pgrp * 64, c0 = cgrp * 64;
    const int tx = threadIdx.x & 63;
    const int ty = threadIdx.x >> 6;            // 0..3

    const float* src = in + (size_t)n * CHW + (size_t)c0 * HW + p0;
    #pragma unroll
    for (int i = 0; i < 16; ++i) {
        const int c = ty + 4 * i;
        t[tx][c] = src[(size_t)c * HW + tx];    // lanes: consecutive p
    }
    __syncthreads();
    __half* dst = wsp + (size_t)n * CHW + (size_t)p0 * C_ + c0;
    #pragma unroll
    for (int i = 0; i < 16; ++i) {
        const int p = ty + 4 * i;
        dst[(size_t)p * C_ + tx] = __float2half(t[p][tx]);  // lanes: consecutive c
    }
}

// ============ kernel 2: gather in fp16 NHWC, half4 paired-sample loads ============
typedef struct { int o; float w; } OW;                  // 8B -> ds_read_b64
typedef struct __attribute__((aligned(8))) { __half2 a, b; } h4;  // dwordx2

__global__ __launch_bounds__(256) void roialign_nhwc_h3(
    const __half* __restrict__ wsp,  // [4][40000][256] fp16
    const float* __restrict__ rois,  // [K][5]
    float* __restrict__ out,         // [K][256][7][7]
    int K)
{
    __shared__ OW     s_ow[NSMP][4];            // 6.27 KB
    __shared__ __half s_out[BINS][132];         // 12.93 KB (132: 8B-aligned rows)

    // halves of one roi are K apart; K=1000 = 0 mod 8 -> same XCD -> shared L2
    const int k    = blockIdx.x % K;
    const int half = blockIdx.x / K;

    const float rx1 = rois[k*5 + 1];
    const float ry1 = rois[k*5 + 2];
    const float rx2 = rois[k*5 + 3];
    const float ry2 = rois[k*5 + 4];
    const int  bidx = (int)rois[k*5 + 0];

    // ALIGNED=True, identical op order to validated rounds
    const float sx = __fsub_rn(__fmul_rn(rx1, 0.25f), 0.5f);
    const float sy = __fsub_rn(__fmul_rn(ry1, 0.25f), 0.5f);
    const float bw = __fdiv_rn(__fmul_rn(__fsub_rn(rx2, rx1), 0.25f), 7.0f);
    const float bh = __fdiv_rn(__fmul_rn(__fsub_rn(ry2, ry1), 0.25f), 7.0f);

    const int tid = threadIdx.x;

    // ---- phase 1: 196 samples -> 4 {pixel offset, weight} pairs each ----
    if (tid < NSMP) {
        const int bin = tid >> 2, q = tid & 3;
        const int ph = bin / PWB, pw = bin - ph * PWB;
        const float cy = (float)ph + ((q >> 1) ? 0.75f : 0.25f);
        const float cx = (float)pw + ((q & 1)  ? 0.75f : 0.25f);
        const float fy = __fadd_rn(sy, __fmul_rn(cy, bh));
        const float fx = __fadd_rn(sx, __fmul_rn(cx, bw));

        const bool valid = (fy >= -1.0f) && (fy <= (float)H_) &&
                           (fx >= -1.0f) && (fx <= (float)W_);

        const float y = fminf(fmaxf(fy, 0.0f), (float)(H_ - 1));
        const float x = fminf(fmaxf(fx, 0.0f), (float)(W_ - 1));
        const int y0 = (int)floorf(y);
        const int x0 = (int)floorf(x);
        const int y1 = min(y0 + 1, H_ - 1);
        const int x1 = min(x0 + 1, W_ - 1);
        const float ly = y - (float)y0;
        const float lx = x - (float)x0;
        const float hy = 1.0f - ly, hx = 1.0f - lx;

        float w00 = hy*hx, w01 = hy*lx, w10 = ly*hx, w11 = ly*lx;
        if (!valid) { w00 = w01 = w10 = w11 = 0.0f; }

        s_ow[tid][0].o = y0 * W_ + x0;  s_ow[tid][0].w = w00;
        s_ow[tid][1].o = y0 * W_ + x1;  s_ow[tid][1].w = w01;
        s_ow[tid][2].o = y1 * W_ + x0;  s_ow[tid][2].w = w10;
        s_ow[tid][3].o = y1 * W_ + x1;  s_ow[tid][3].w = w11;
    }
    __syncthreads();

    // ---- phase 2: wave = bin, lane group (lane>>5) = gather parity ----
    // lane covers channels half*128 + (lane&31)*4 .. +3 ; one wave-instr
    // = 2 sample-pixels x 128ch = 512B burst (global_load_dwordx2)
    const int wv   = tid >> 6;                  // 0..3
    const int lane = tid & 63;
    const int grp  = lane >> 5;                 // 0/1: which gather of the pair
    const int cl4  = lane & 31;                 // channel quad within half
    // base in half4 units: pixel o is at o*64 + half*32 + cl4
    const h4* __restrict__ img4 =
        (const h4*)(wsp + (size_t)bidx * CHW) + (half * 32 + cl4);

    #pragma unroll 2
    for (int bin = wv; bin < BINS; bin += 4) {
        float a0 = 0, a1 = 0, a2 = 0, a3 = 0;
        #pragma unroll
        for (int j = 0; j < 8; ++j) {
            // gather index g = j*2 + grp ; s4 = g>>2, q = g&3
            const int g = j * 2 + grp;
            const OW ow = s_ow[bin * 4 + (g >> 2)][g & 3];   // 2-addr broadcast
            const h4 f = img4[(size_t)ow.o * 64];
            const float2 flo = __half22float2(f.a);
            const float2 fhi = __half22float2(f.b);
            a0 = fmaf(ow.w, flo.x, a0);
            a1 = fmaf(ow.w, flo.y, a1);
            a2 = fmaf(ow.w, fhi.x, a2);
            a3 = fmaf(ow.w, fhi.y, a3);
        }
        // combine the two gather-parity halves (channels match across xor 32)
        a0 += __shfl_xor(a0, 32);
        a1 += __shfl_xor(a1, 32);
        a2 += __shfl_xor(a2, 32);
        a3 += __shfl_xor(a3, 32);
        if (grp == 0) {
            __half2* dst = (__half2*)&s_out[bin][4 * cl4];
            dst[0] = __floats2half2_rn(a0 * 0.25f, a1 * 0.25f);
            dst[1] = __floats2half2_rn(a2 * 0.25f, a3 * 0.25f);
        }
    }
    __syncthreads();

    // ---- coalesced output write: [ch][bin] order ----
    float* __restrict__ ob = out + ((size_t)k * C_ + half * 128) * BINS;
    #pragma unroll 1
    for (int e = tid; e < 128 * BINS; e += 256) {
        const int ch = e / BINS, bn = e - ch * BINS;
        ob[e] = __half2float(s_out[bn][ch]);
    }
}

// ============ fallback (round-4 kernel, fp32 direct) ============
#define CSPLIT 4
#define CB     (C_/CSPLIT)
#define NCG    5
typedef struct __attribute__((aligned(4))) { float x, y; } f2u;

__global__ __launch_bounds__(256) void roialign_fwd_fb(
    const float* __restrict__ input, const float* __restrict__ rois,
    float* __restrict__ out, int K)
{
    const int k  = blockIdx.x / CSPLIT;
    const int cs = blockIdx.x - k * CSPLIT;
    if (k >= K) return;
    const int tid = threadIdx.x;
    const int bin = tid % BINS;
    const int cg  = tid / BINS;
    if (cg >= NCG) return;

    const float rx1 = rois[k*5+1], ry1 = rois[k*5+2];
    const float rx2 = rois[k*5+3], ry2 = rois[k*5+4];
    const int  bidx = (int)rois[k*5+0];
    const float sx = __fsub_rn(__fmul_rn(rx1,0.25f),0.5f);
    const float sy = __fsub_rn(__fmul_rn(ry1,0.25f),0.5f);
    const float bw = __fdiv_rn(__fmul_rn(__fsub_rn(rx2,rx1),0.25f),7.0f);
    const float bh = __fdiv_rn(__fmul_rn(__fsub_rn(ry2,ry1),0.25f),7.0f);
    const int ph = bin / PWB, pw = bin - ph * PWB;

    int off0[4], off1[4];
    float wA0[4], wB0[4], wA1[4], wB1[4];
    #pragma unroll
    for (int q = 0; q < 4; ++q) {
        const float cy = (float)ph + ((q >> 1) ? 0.75f : 0.25f);
        const float cx = (float)pw + ((q & 1)  ? 0.75f : 0.25f);
        const float fy = __fadd_rn(sy, __fmul_rn(cy, bh));
        const float fx = __fadd_rn(sx, __fmul_rn(cx, bw));
        const bool valid = (fy >= -1.0f) && (fy <= (float)H_) &&
                           (fx >= -1.0f) && (fx <= (float)W_);
        const float y = fminf(fmaxf(fy, 0.0f), (float)(H_-1));
        const float x = fminf(fmaxf(fx, 0.0f), (float)(W_-1));
        const int y0 = (int)floorf(y);
        const int x0 = (int)floorf(x);
        const int y1 = min(y0 + 1, H_-1);
        const float ly = y - (float)y0, lx = x - (float)x0;
        const float hy = 1.0f - ly, hx = 1.0f - lx;
        float w00 = hy*hx, w01 = hy*lx, w10 = ly*hx, w11 = ly*lx;
        if (!valid) { w00 = w01 = w10 = w11 = 0.0f; }
        const int xb = min(x0, W_-2);
        const bool xcl = (x0 != xb);
        wA0[q] = xcl ? 0.0f : w00;  wB0[q] = xcl ? w00 : w01;
        wA1[q] = xcl ? 0.0f : w10;  wB1[q] = xcl ? w10 : w11;
        off0[q] = y0 * W_ + xb;     off1[q] = y1 * W_ + xb;
    }
    const float* __restrict__ img  = input + ((size_t)bidx*C_ + cs*CB) * HW;
    float* __restrict__       outk = out   + ((size_t)k   *C_ + cs*CB) * BINS;
    #pragma unroll 2
    for (int c = cg; c < CB; c += NCG) {
        const float* __restrict__ ch = img + (size_t)c * HW;
        float acc = 0.0f;
        #pragma unroll
        for (int q = 0; q < 4; ++q) {
            const f2u p0 = *(const f2u*)(ch + off0[q]);
            const f2u p1 = *(const f2u*)(ch + off1[q]);
            acc += wA0[q]*p0.x + wB0[q]*p0.y + wA1[q]*p1.x + wB1[q]*p1.y;
        }
        outk[c * BINS + bin] = acc * 0.25f;
    }
}

extern "C" void kernel_launch(void* const* d_in, const int* in_sizes, int n_in,
                              void* d_out, int out_size, void* d_ws, size_t ws_size,
                              hipStream_t stream) {
    const float* input = (const float*)d_in[0];
    const float* rois  = (const float*)d_in[1];
    float* out = (float*)d_out;
    const int K = in_sizes[1] / 5;
    const int N = in_sizes[0] / (int)CHW;       // 4 images

    const size_t need = (size_t)N * CHW * sizeof(__half);   // 81.92 MB
    if (ws_size >= need) {
        __half* wsp = (__half*)d_ws;
        nchw_to_nhwc_h<<<N * 2500, 256, 0, stream>>>(input, wsp);
        roialign_nhwc_h3<<<K * 2, 256, 0, stream>>>(wsp, rois, out, K);
    } else {
        roialign_fwd_fb<<<K * CSPLIT, 256, 0, stream>>>(input, rois, out, K);
    }
}

// Round 11
// 82.922 us; speedup vs baseline: 1.0367x; 1.0020x over previous
//
#include <hip/hip_runtime.h>
#include <hip/hip_fp16.h>

#define C_    256
#define H_    200
#define W_    200
#define HW    (H_*W_)        // 40000
#define CHW   ((size_t)C_*HW)
#define PWB   7
#define BINS  49
#define NSMP  196            // 49 bins * 4 subsamples, bin-major

typedef struct __attribute__((aligned(8))) { __half2 a, b; } h4;  // dwordx2
typedef struct { int o; float w; } OW;                            // 8B

// ============ kernel 1: NCHW fp32 -> NHWC fp16 transpose ============
// write phase: half4 per lane -> 512B per wave-instr (was scalar __half)
__global__ __launch_bounds__(256) void nchw_to_nhwc_h(
    const float* __restrict__ in, __half* __restrict__ wsp)
{
    __shared__ float t[64][65];
    const int pgrp = blockIdx.x % 625;          // 625 * 64 = 40000 pixels
    const int cgrp = (blockIdx.x / 625) & 3;    // 4 * 64 = 256 channels
    const int n    = blockIdx.x / 2500;
    const int p0 = pgrp * 64, c0 = cgrp * 64;
    const int tid = threadIdx.x;
    const int tx = tid & 63;
    const int ty = tid >> 6;                    // 0..3

    const float* src = in + (size_t)n * CHW + (size_t)c0 * HW + p0;
    #pragma unroll
    for (int i = 0; i < 16; ++i) {
        const int c = ty + 4 * i;
        t[tx][c] = src[(size_t)c * HW + tx];    // lanes: consecutive p
    }
    __syncthreads();

    __half* dst = wsp + (size_t)n * CHW + (size_t)p0 * C_ + c0;
    const int u  = tid & 15;                    // channel quad: c = 4u
    const int pr = tid >> 4;                    // 0..15
    #pragma unroll
    for (int i = 0; i < 4; ++i) {
        const int p = pr + 16 * i;
        h4 v;
        v.a = __floats2half2_rn(t[p][4*u + 0], t[p][4*u + 1]);
        v.b = __floats2half2_rn(t[p][4*u + 2], t[p][4*u + 3]);
        *(h4*)&dst[(size_t)p * C_ + 4*u] = v;   // 8B store, 8B-aligned
    }
}

// ============ kernel 2: gather, 512-thread block = one roi ============
// wave = bin; 64 lanes x half4 = one full 256-ch pixel row (512B) per instr
__global__ __launch_bounds__(512, 8) void roialign_nhwc_h4(
    const __half* __restrict__ wsp,  // [4][40000][256] fp16
    const float* __restrict__ rois,  // [K][5]
    float* __restrict__ out,         // [K][256][7][7]
    int K)
{
    __shared__ OW     s_ow[NSMP][4];            // 6.27 KB
    __shared__ __half s_out[BINS][260];         // 25.48 KB (260: 8B-aligned rows)

    const int k = blockIdx.x;

    const float rx1 = rois[k*5 + 1];
    const float ry1 = rois[k*5 + 2];
    const float rx2 = rois[k*5 + 3];
    const float ry2 = rois[k*5 + 4];
    const int  bidx = (int)rois[k*5 + 0];

    // ALIGNED=True, identical op order to validated rounds
    const float sx = __fsub_rn(__fmul_rn(rx1, 0.25f), 0.5f);
    const float sy = __fsub_rn(__fmul_rn(ry1, 0.25f), 0.5f);
    const float bw = __fdiv_rn(__fmul_rn(__fsub_rn(rx2, rx1), 0.25f), 7.0f);
    const float bh = __fdiv_rn(__fmul_rn(__fsub_rn(ry2, ry1), 0.25f), 7.0f);

    const int tid = threadIdx.x;

    // ---- phase 1: 196 samples -> 4 {pixel offset, weight} pairs each ----
    if (tid < NSMP) {
        const int bin = tid >> 2, q = tid & 3;
        const int ph = bin / PWB, pw = bin - ph * PWB;
        const float cy = (float)ph + ((q >> 1) ? 0.75f : 0.25f);
        const float cx = (float)pw + ((q & 1)  ? 0.75f : 0.25f);
        const float fy = __fadd_rn(sy, __fmul_rn(cy, bh));
        const float fx = __fadd_rn(sx, __fmul_rn(cx, bw));

        const bool valid = (fy >= -1.0f) && (fy <= (float)H_) &&
                           (fx >= -1.0f) && (fx <= (float)W_);

        const float y = fminf(fmaxf(fy, 0.0f), (float)(H_ - 1));
        const float x = fminf(fmaxf(fx, 0.0f), (float)(W_ - 1));
        const int y0 = (int)floorf(y);
        const int x0 = (int)floorf(x);
        const int y1 = min(y0 + 1, H_ - 1);
        const int x1 = min(x0 + 1, W_ - 1);
        const float ly = y - (float)y0;
        const float lx = x - (float)x0;
        const float hy = 1.0f - ly, hx = 1.0f - lx;

        float w00 = hy*hx, w01 = hy*lx, w10 = ly*hx, w11 = ly*lx;
        if (!valid) { w00 = w01 = w10 = w11 = 0.0f; }

        s_ow[tid][0].o = y0 * W_ + x0;  s_ow[tid][0].w = w00;
        s_ow[tid][1].o = y0 * W_ + x1;  s_ow[tid][1].w = w01;
        s_ow[tid][2].o = y1 * W_ + x0;  s_ow[tid][2].w = w10;
        s_ow[tid][3].o = y1 * W_ + x1;  s_ow[tid][3].w = w11;
    }
    __syncthreads();

    // ---- phase 2: wave = bin, lane = channel quad (half4) ----
    const int wv   = tid >> 6;                  // 0..7
    const int lane = tid & 63;
    const h4* __restrict__ img4 = (const h4*)(wsp + (size_t)bidx * CHW) + lane;

    #pragma unroll 1
    for (int bin = wv; bin < BINS; bin += 8) {
        float a0 = 0, a1 = 0, a2 = 0, a3 = 0;
        #pragma unroll
        for (int s = 0; s < 16; ++s) {
            const OW ow = s_ow[bin * 4 + (s >> 2)][s & 3];  // broadcast
            const h4 f = img4[(size_t)ow.o * 64];           // 512B/wave burst
            const float2 flo = __half22float2(f.a);
            const float2 fhi = __half22float2(f.b);
            a0 = fmaf(ow.w, flo.x, a0);
            a1 = fmaf(ow.w, flo.y, a1);
            a2 = fmaf(ow.w, fhi.x, a2);
            a3 = fmaf(ow.w, fhi.y, a3);
        }
        h4 r;
        r.a = __floats2half2_rn(a0 * 0.25f, a1 * 0.25f);
        r.b = __floats2half2_rn(a2 * 0.25f, a3 * 0.25f);
        *(h4*)&s_out[bin][4 * lane] = r;
    }
    __syncthreads();

    // ---- coalesced output write: [ch][bin] order, full roi ----
    float* __restrict__ ob = out + (size_t)k * C_ * BINS;
    #pragma unroll 1
    for (int e = tid; e < C_ * BINS; e += 512) {
        const int ch = e / BINS, bn = e - ch * BINS;
        ob[e] = __half2float(s_out[bn][ch]);
    }
}

// ============ fallback (round-4 kernel, fp32 direct) ============
#define CSPLIT 4
#define CB     (C_/CSPLIT)
#define NCG    5
typedef struct __attribute__((aligned(4))) { float x, y; } f2u;

__global__ __launch_bounds__(256) void roialign_fwd_fb(
    const float* __restrict__ input, const float* __restrict__ rois,
    float* __restrict__ out, int K)
{
    const int k  = blockIdx.x / CSPLIT;
    const int cs = blockIdx.x - k * CSPLIT;
    if (k >= K) return;
    const int tid = threadIdx.x;
    const int bin = tid % BINS;
    const int cg  = tid / BINS;
    if (cg >= NCG) return;

    const float rx1 = rois[k*5+1], ry1 = rois[k*5+2];
    const float rx2 = rois[k*5+3], ry2 = rois[k*5+4];
    const int  bidx = (int)rois[k*5+0];
    const float sx = __fsub_rn(__fmul_rn(rx1,0.25f),0.5f);
    const float sy = __fsub_rn(__fmul_rn(ry1,0.25f),0.5f);
    const float bw = __fdiv_rn(__fmul_rn(__fsub_rn(rx2,rx1),0.25f),7.0f);
    const float bh = __fdiv_rn(__fmul_rn(__fsub_rn(ry2,ry1),0.25f),7.0f);
    const int ph = bin / PWB, pw = bin - ph * PWB;

    int off0[4], off1[4];
    float wA0[4], wB0[4], wA1[4], wB1[4];
    #pragma unroll
    for (int q = 0; q < 4; ++q) {
        const float cy = (float)ph + ((q >> 1) ? 0.75f : 0.25f);
        const float cx = (float)pw + ((q & 1)  ? 0.75f : 0.25f);
        const float fy = __fadd_rn(sy, __fmul_rn(cy, bh));
        const float fx = __fadd_rn(sx, __fmul_rn(cx, bw));
        const bool valid = (fy >= -1.0f) && (fy <= (float)H_) &&
                           (fx >= -1.0f) && (fx <= (float)W_);
        const float y = fminf(fmaxf(fy, 0.0f), (float)(H_-1));
        const float x = fminf(fmaxf(fx, 0.0f), (float)(W_-1));
        const int y0 = (int)floorf(y);
        const int x0 = (int)floorf(x);
        const int y1 = min(y0 + 1, H_-1);
        const float ly = y - (float)y0, lx = x - (float)x0;
        const float hy = 1.0f - ly, hx = 1.0f - lx;
        float w00 = hy*hx, w01 = hy*lx, w10 = ly*hx, w11 = ly*lx;
        if (!valid) { w00 = w01 = w10 = w11 = 0.0f; }
        const int xb = min(x0, W_-2);
        const bool xcl = (x0 != xb);
        wA0[q] = xcl ? 0.0f : w00;  wB0[q] = xcl ? w00 : w01;
        wA1[q] = xcl ? 0.0f : w10;  wB1[q] = xcl ? w10 : w11;
        off0[q] = y0 * W_ + xb;     off1[q] = y1 * W_ + xb;
    }
    const float* __restrict__ img  = input + ((size_t)bidx*C_ + cs*CB) * HW;
    float* __restrict__       outk = out   + ((size_t)k   *C_ + cs*CB) * BINS;
    #pragma unroll 2
    for (int c = cg; c < CB; c += NCG) {
        const float* __restrict__ ch = img + (size_t)c * HW;
        float acc = 0.0f;
        #pragma unroll
        for (int q = 0; q < 4; ++q) {
            const f2u p0 = *(const f2u*)(ch + off0[q]);
            const f2u p1 = *(const f2u*)(ch + off1[q]);
            acc += wA0[q]*p0.x + wB0[q]*p0.y + wA1[q]*p1.x + wB1[q]*p1.y;
        }
        outk[c * BINS + bin] = acc * 0.25f;
    }
}

extern "C" void kernel_launch(void* const* d_in, const int* in_sizes, int n_in,
                              void* d_out, int out_size, void* d_ws, size_t ws_size,
                              hipStream_t stream) {
    const float* input = (const float*)d_in[0];
    const float* rois  = (const float*)d_in[1];
    float* out = (float*)d_out;
    const int K = in_sizes[1] / 5;
    const int N = in_sizes[0] / (int)CHW;       // 4 images

    const size_t need = (size_t)N * CHW * sizeof(__half);   // 81.92 MB
    if (ws_size >= need) {
        __half* wsp = (__half*)d_ws;
        nchw_to_nhwc_h<<<N * 2500, 256, 0, stream>>>(input, wsp);
        roialign_nhwc_h4<<<K, 512, 0, stream>>>(wsp, rois, out, K);
    } else {
        roialign_fwd_fb<<<K * CSPLIT, 256, 0, stream>>>(input, rois, out, K);
    }
}